// Round 10
// baseline (784.086 us; speedup 1.0000x reference)
//
#include <hip/hip_runtime.h>
#include <math.h>

#define B 8
#define C 64
#define L 2048
#define CS 256
#define BCL  (B*C*L)    // 1048576
#define BCSL (B*CS*L)   // 4194304
#define HS 0.25f

typedef unsigned short u16;
typedef unsigned int   u32;
typedef __attribute__((ext_vector_type(8))) short sh8;
typedef __attribute__((ext_vector_type(4))) float f4;
typedef __attribute__((ext_vector_type(8))) unsigned short us8;
typedef __attribute__((ext_vector_type(4))) unsigned short us4;

__device__ __forceinline__ float gelu(float x) {
    return 0.5f * x * (1.0f + erff(x * 0.70710678118654752440f));
}
__device__ __forceinline__ u16 f2b(float f) {
    u32 u = __float_as_uint(f);
    u32 r = u + 0x7FFFu + ((u >> 16) & 1u);
    return (u16)(r >> 16);
}
__device__ __forceinline__ float b2f(u16 h) {
    return __uint_as_float(((u32)h) << 16);
}

// ---------- weight prep: fp32 [oc][ic][k] -> bf16 A-frag order ----------
__global__ __launch_bounds__(256) void prep_k(const float* __restrict__ w,
        u16* __restrict__ dst, int IC, int OC) {
    int idx = blockIdx.x * 256 + threadIdx.x;
    int OCG = OC >> 4;
    int j = idx & 7, lane = (idx >> 3) & 63, t = idx >> 9;
    int ocg = t % OCG, c = t / OCG;
    int oc = ocg * 16 + (lane & 15);
    int K = c * 32 + ((lane >> 4) & 3) * 8 + j;
    int kk = K / IC, ic = K % IC;
    dst[idx] = f2b(w[((size_t)oc * IC + ic) * 3 + kk]);
}

// ---------- all 25 cond vectors ----------
__global__ void cond25_k(const float* __restrict__ tw1, const float* __restrict__ tb1,
                         const float* __restrict__ tw2, const float* __restrict__ tb2,
                         const float* __restrict__ cw, const float* __restrict__ cb,
                         float* __restrict__ condall) {
    __shared__ float te1[16], te2[16];
    int tix = blockIdx.x;
    int tid = threadIdx.x;
    double add[6] = {0.0, 0.25/5.0, 3.0*0.25/10.0, 4.0*0.25/5.0, 8.0*0.25/9.0, 0.25};
    float t = (tix == 24) ? 1.0f : (float)((double)(tix / 6) * 0.25 + add[tix % 6]);
    if (tid < 16) te1[tid] = gelu(t * tw1[tid] + tb1[tid]);
    __syncthreads();
    if (tid < 16) {
        float s = tb2[tid];
        for (int k = 0; k < 16; ++k) s += te1[k] * tw2[tid*16+k];
        te2[tid] = s;
    }
    __syncthreads();
    float s = cb[tid];
    for (int j = 0; j < 16; ++j) s += te2[j] * cw[tid*16+j];
    condall[tix*128 + tid] = s;
}

// ======================================================================
// conv stack: conv1(FiLM,GELU) -> conv2(GELU) -> conv3 accumulators.
// Unified r coordinate: global pos = l0 - 6 + r.  s-output rows [LO, LO+N).
// ======================================================================
template<int LO, int N, int NF3>
__device__ __forceinline__ void conv_stack(
    int tid, int l0,
    const u16 (&xs)[28][264], u16 (&h1)[28][72], u16 (&h2)[28][72],
    const u16* __restrict__ wp1, const float* __restrict__ kb1,
    const float* __restrict__ cd,
    const u16* __restrict__ wp2, const float* __restrict__ kb2,
    f4 (&a3)[NF3][4], const u16* __restrict__ wp3)
{
    constexpr int NF1 = (N + 4 + 15) / 16;
    constexpr int NF2 = (N + 2 + 15) / 16;
    constexpr int XHI  = LO + N + 2;   // max xs row legitimately read
    constexpr int H1HI = LO + N + 1;
    constexpr int H2HI = LO + N;
    const int wave = tid >> 6, lane = tid & 63;
    const int nlo = lane & 15, quad = lane >> 4;

    // ---- conv1: K=768, out rows [LO-2, LO+N+2) ----
    {
        f4 acc[NF1];
        #pragma unroll
        for (int j = 0; j < NF1; ++j) acc[j] = f4{0.f,0.f,0.f,0.f};
        const sh8* w1 = (const sh8*)wp1;
        for (int c = 0; c < 24; ++c) {
            int kk = c >> 3, ic0 = (c & 7) << 5;
            sh8 A = w1[(c*4 + wave)*64 + lane];
            #pragma unroll
            for (int j = 0; j < NF1; ++j) {
                int row = (LO - 3) + 16*j + nlo + kk;
                row = row > XHI ? XHI : row;
                sh8 Bv = *(const sh8*)&xs[row][ic0 + quad*8];
                acc[j] = __builtin_amdgcn_mfma_f32_16x16x32_bf16(A, Bv, acc[j], 0, 0, 0);
            }
        }
        #pragma unroll
        for (int j = 0; j < NF1; ++j) {
            int p = (LO - 2) + 16*j + nlo;
            if (p < LO + N + 2) {
                int gp = l0 - 6 + p;
                bool ok = (gp >= 0) && (gp < L);
                #pragma unroll
                for (int reg = 0; reg < 4; ++reg) {
                    int oc = wave*16 + quad*4 + reg;
                    float v = (1.f + cd[oc]) * (acc[j][reg] + kb1[oc]) + cd[64+oc];
                    h1[p][oc] = ok ? f2b(gelu(v)) : (u16)0;
                }
            }
        }
    }
    __syncthreads();

    // ---- conv2: K=192, out rows [LO-1, LO+N+1) ----
    {
        f4 acc[NF2];
        #pragma unroll
        for (int j = 0; j < NF2; ++j) acc[j] = f4{0.f,0.f,0.f,0.f};
        const sh8* w2 = (const sh8*)wp2;
        #pragma unroll
        for (int c = 0; c < 6; ++c) {
            int kk = c >> 1, ic0 = (c & 1) << 5;
            sh8 A = w2[(c*4 + wave)*64 + lane];
            #pragma unroll
            for (int j = 0; j < NF2; ++j) {
                int row = (LO - 2) + 16*j + nlo + kk;
                row = row > H1HI ? H1HI : row;
                sh8 Bv = *(const sh8*)&h1[row][ic0 + quad*8];
                acc[j] = __builtin_amdgcn_mfma_f32_16x16x32_bf16(A, Bv, acc[j], 0, 0, 0);
            }
        }
        #pragma unroll
        for (int j = 0; j < NF2; ++j) {
            int q = (LO - 1) + 16*j + nlo;
            if (q < LO + N + 1) {
                int gq = l0 - 6 + q;
                bool ok = (gq >= 0) && (gq < L);
                #pragma unroll
                for (int reg = 0; reg < 4; ++reg) {
                    int oc = wave*16 + quad*4 + reg;
                    h2[q][oc] = ok ? f2b(gelu(acc[j][reg] + kb2[oc])) : (u16)0;
                }
            }
        }
    }
    __syncthreads();

    // ---- conv3: K=192, 256 oc, out rows [LO, LO+N) ----
    {
        #pragma unroll
        for (int j = 0; j < NF3; ++j)
            #pragma unroll
            for (int mf = 0; mf < 4; ++mf) a3[j][mf] = f4{0.f,0.f,0.f,0.f};
        const sh8* w3 = (const sh8*)wp3;
        #pragma unroll
        for (int c = 0; c < 6; ++c) {
            int kk = c >> 1, ic0 = (c & 1) << 5;
            #pragma unroll
            for (int j = 0; j < NF3; ++j) {
                int row = (LO - 1) + 16*j + nlo + kk;
                row = row > H2HI ? H2HI : row;
                sh8 Bv = *(const sh8*)&h2[row][ic0 + quad*8];
                #pragma unroll
                for (int mf = 0; mf < 4; ++mf) {
                    sh8 A = w3[(c*16 + wave*4 + mf)*64 + lane];
                    a3[j][mf] = __builtin_amdgcn_mfma_f32_16x16x32_bf16(A, Bv, a3[j][mf], 0, 0, 0);
                }
            }
        }
    }
}

// ======================================================================
// Pair kernel: two fused ode_f stages.
// PH 0: s1 (A) + s2 (B, s1 from LDS).   writes s1,s2.
// PH 1: s3 (A) + s4 (B, s3 from LDS).   writes s3,s4.
// PH 2: s5 (A, LDS only) + s6 (B) + y-update epilogue.
// 16-pos out tiles, grid (128,8). A-stage covers rows [3,25) (22 rows).
// ======================================================================
template<int PH, int LAST>
__global__ __launch_bounds__(256) void pair_k(
    const u16* __restrict__ ybin,
    const u16* __restrict__ s1g, const u16* __restrict__ s2g,
    const u16* __restrict__ s3g, const u16* __restrict__ s4g,
    u16* __restrict__ outA, u16* __restrict__ outB,
    const u16* __restrict__ wp1, const float* __restrict__ kb1,
    const u16* __restrict__ wp2, const float* __restrict__ kb2,
    const u16* __restrict__ wp3, const float* __restrict__ kb3,
    const float* __restrict__ condall, int step,
    float* __restrict__ ytr, u16* __restrict__ ybo, float* __restrict__ outp)
{
    __shared__ u16 xs[28][264];
    __shared__ u16 sL[22][264];
    __shared__ u16 h1[28][72];
    __shared__ u16 h2[28][72];
    __shared__ u16 ypart[(PH == 2) ? 16 : 1][264];
    constexpr int NP = (PH == 0) ? 1 : (PH == 1) ? 3 : 5;
    const int tid = threadIdx.x;
    const int l0 = blockIdx.x * 16;
    const int b  = blockIdx.y;
    const u16* P[5] = {ybin, s1g, s2g, s3g, s4g};

    float cA[5] = {1.f, 0.f, 0.f, 0.f, 0.f};
    float cB[5] = {1.f, 0.f, 0.f, 0.f, 0.f};
    float cL = 0.f, d1 = 0.f, d3 = 0.f, d4 = 0.f, dL = 0.f;
    if (PH == 0) {
        cL = HS * (1.f/5.f);
    } else if (PH == 1) {
        cA[1] = HS*(3.f/40.f);  cA[2] = HS*(9.f/40.f);
        cB[1] = HS*(44.f/45.f); cB[2] = -HS*(56.f/15.f); cL = HS*(32.f/9.f);
    } else {
        cA[1] = HS*(19372.f/6561.f); cA[2] = -HS*(25360.f/2187.f);
        cA[3] = HS*(64448.f/6561.f); cA[4] = -HS*(212.f/729.f);
        cB[1] = HS*(9017.f/3168.f);  cB[2] = -HS*(355.f/33.f);
        cB[3] = HS*(46732.f/5247.f); cB[4] = HS*(49.f/176.f);
        cL = -HS*(5103.f/18656.f);
        d1 = HS*(35.f/384.f); d3 = HS*(500.f/1113.f); d4 = HS*(125.f/192.f);
        dL = -HS*(2187.f/6784.f);
    }

    // ---- pass A staging: 28 rows, pos = l0-6+r ----
    #pragma unroll
    for (int it = 0; it < 4; ++it) {
        int idx = it * 256 + tid;
        if (idx < 28 * 32) {
            int r = idx >> 5, c8 = idx & 31;
            int gl = l0 - 6 + r;
            us8 val;
            if (gl >= 0 && gl < L) {
                size_t a = ((size_t)b * L + gl) * 256 + c8 * 8;
                if (NP == 1) {
                    val = *(const us8*)(P[0] + a);
                } else {
                    us8 v0 = *(const us8*)(P[0] + a);
                    float f[8];
                    #pragma unroll
                    for (int j = 0; j < 8; ++j) f[j] = b2f(v0[j]);
                    #pragma unroll
                    for (int t = 1; t < NP; ++t) {
                        us8 vt = *(const us8*)(P[t] + a);
                        #pragma unroll
                        for (int j = 0; j < 8; ++j) f[j] += cA[t] * b2f(vt[j]);
                    }
                    #pragma unroll
                    for (int j = 0; j < 8; ++j) val[j] = f2b(f[j]);
                }
            } else {
                #pragma unroll
                for (int j = 0; j < 8; ++j) val[j] = 0;
            }
            *(us8*)&xs[r][c8 * 8] = val;
        }
    }
    __syncthreads();

    const int wave = tid >> 6, lane = tid & 63;
    const int nlo = lane & 15, quad = lane >> 4;

    // ---- stage A conv stack -> sL (+ global write for owned rows, PH<2) ----
    {
        const float* cdA = condall + (step*6 + PH*2) * 128;
        f4 a3[2][4];
        conv_stack<3, 22, 2>(tid, l0, xs, h1, h2, wp1, kb1, cdA, wp2, kb2, a3, wp3);
        #pragma unroll
        for (int j = 0; j < 2; ++j) {
            int p = 3 + 16*j + nlo;
            if (p < 25) {
                int gp = l0 - 6 + p;
                bool ok = (gp >= 0) && (gp < L);
                #pragma unroll
                for (int mf = 0; mf < 4; ++mf) {
                    int baseoc = (wave*4 + mf)*16 + quad*4;
                    us4 pk;
                    #pragma unroll
                    for (int reg = 0; reg < 4; ++reg) {
                        float v = a3[j][mf][reg] + kb3[baseoc + reg];
                        pk[reg] = ok ? f2b(v) : (u16)0;
                    }
                    *(us4*)&sL[p - 3][baseoc] = pk;
                    if (PH < 2 && p >= 6 && p < 22)
                        *(us4*)(outA + ((size_t)b * L + gp) * 256 + baseoc) = pk;
                }
            }
        }
    }
    __syncthreads();

    // ---- pass B staging: rows r=3..24 in place (re-read globals + sL) ----
    #pragma unroll
    for (int it = 0; it < 3; ++it) {
        int idx = it * 256 + tid;
        if (idx < 22 * 32) {
            int rr = idx >> 5, c8 = idx & 31;
            int gl = l0 - 3 + rr;
            us8 val;
            if (gl >= 0 && gl < L) {
                size_t a = ((size_t)b * L + gl) * 256 + c8 * 8;
                us8 sl = *(const us8*)&sL[rr][c8 * 8];
                us8 v0 = *(const us8*)(P[0] + a);
                float f[8], yp[8];
                #pragma unroll
                for (int j = 0; j < 8; ++j) {
                    f[j] = b2f(v0[j]) + cL * b2f(sl[j]);
                    yp[j] = (PH == 2) ? dL * b2f(sl[j]) : 0.f;
                }
                #pragma unroll
                for (int t = 1; t < NP; ++t) {
                    us8 vt = *(const us8*)(P[t] + a);
                    #pragma unroll
                    for (int j = 0; j < 8; ++j) {
                        float bv = b2f(vt[j]);
                        f[j] += cB[t] * bv;
                        if (PH == 2 && (t == 1 || t == 3 || t == 4))
                            yp[j] += ((t == 1) ? d1 : (t == 3) ? d3 : d4) * bv;
                    }
                }
                #pragma unroll
                for (int j = 0; j < 8; ++j) val[j] = f2b(f[j]);
                if (PH == 2 && rr >= 3 && rr < 19) {
                    us8 ypk;
                    #pragma unroll
                    for (int j = 0; j < 8; ++j) ypk[j] = f2b(yp[j]);
                    *(us8*)&ypart[rr - 3][c8 * 8] = ypk;
                }
            } else {
                #pragma unroll
                for (int j = 0; j < 8; ++j) val[j] = 0;
            }
            *(us8*)&xs[rr + 3][c8 * 8] = val;
        }
    }
    __syncthreads();

    // ---- stage B conv stack ----
    const float* cdB = condall + (step*6 + PH*2 + 1) * 128;
    f4 b3[1][4];
    conv_stack<6, 16, 1>(tid, l0, xs, h1, h2, wp1, kb1, cdB, wp2, kb2, b3, wp3);

    // ---- epilogue ----
    const int pos = l0 + nlo;
    if (PH < 2) {
        #pragma unroll
        for (int mf = 0; mf < 4; ++mf) {
            int baseoc = (wave*4 + mf)*16 + quad*4;
            us4 pk;
            #pragma unroll
            for (int reg = 0; reg < 4; ++reg)
                pk[reg] = f2b(b3[0][mf][reg] + kb3[baseoc + reg]);
            *(us4*)(outB + ((size_t)b * L + pos) * 256 + baseoc) = pk;
        }
    } else {
        const float cy6 = HS * (11.f/84.f);
        #pragma unroll
        for (int mf = 0; mf < 4; ++mf) {
            int baseoc = (wave*4 + mf)*16 + quad*4;
            size_t ta = ((size_t)b * L + pos) * 256 + baseoc;
            us4 yp4 = *(const us4*)&ypart[nlo][baseoc];
            f4 y4 = *(const f4*)(ytr + ta);
            us4 pk; f4 yo;
            #pragma unroll
            for (int reg = 0; reg < 4; ++reg) {
                int oc = baseoc + reg;
                float s6 = b3[0][mf][reg] + kb3[oc];
                float yv = y4[reg] + b2f(yp4[reg]) + cy6 * s6;
                yo[reg] = yv;
                pk[reg] = f2b(yv);
                if (LAST)
                    outp[(((size_t)(oc >> 6) * B + b) * 64 + (oc & 63)) * L + pos] = yv;
            }
            if (!LAST) *(f4*)(ytr + ta) = yo;
            *(us4*)(ybo + ta) = pk;
        }
    }
}

// ---------- final dx = ode_f(1.0, y) + ecloss (verified in round 7) ----------
__global__ __launch_bounds__(256) void dxec_k(
    const u16* __restrict__ ybi,
    const u16* __restrict__ wp1, const float* __restrict__ kb1,
    const u16* __restrict__ wp2, const float* __restrict__ kb2,
    const u16* __restrict__ wp3, const float* __restrict__ kb3,
    const float* __restrict__ condall,
    const float* __restrict__ stacked, double* __restrict__ inner)
{
    __shared__ u16 xs[22][264];
    __shared__ u16 h1[22][72];
    __shared__ u16 h2[20][72];
    __shared__ double sred[4];
    const int tid = threadIdx.x;
    const int bx = blockIdx.x;
    const int tile = ((bx & 7) << 4) | (bx >> 3);
    const int l0 = tile * 16;
    const int b = blockIdx.y;

    #pragma unroll
    for (int it = 0; it < 3; ++it) {
        int idx = it * 256 + tid;
        if (idx < 22 * 32) {
            int r = idx >> 5, co = (idx & 31) * 8;
            int gl = l0 - 3 + r;
            us8 v = {};
            if (gl >= 0 && gl < L) v = *(const us8*)(ybi + ((size_t)b*L + gl)*256 + co);
            *(us8*)&xs[r][co] = v;
        }
    }
    __syncthreads();

    const int wave = tid >> 6, lane = tid & 63;
    const int nlo = lane & 15, quad = lane >> 4;

    {
        f4 acc[2];
        acc[0] = f4{0.f,0.f,0.f,0.f}; acc[1] = acc[0];
        const sh8* w1 = (const sh8*)wp1;
        for (int c = 0; c < 24; ++c) {
            int kk = c >> 3, ic0 = (c & 7) << 5;
            sh8 A = w1[(c*4 + wave)*64 + lane];
            #pragma unroll
            for (int j = 0; j < 2; ++j) {
                int row = 16*j + nlo + kk;
                row = row > 21 ? 21 : row;
                sh8 Bv = *(const sh8*)&xs[row][ic0 + quad*8];
                acc[j] = __builtin_amdgcn_mfma_f32_16x16x32_bf16(A, Bv, acc[j], 0, 0, 0);
            }
        }
        const float* cd = condall + 24*128;
        #pragma unroll
        for (int j = 0; j < 2; ++j) {
            int p = 1 + 16*j + nlo;
            if (p < 22) {
                int gp = l0 - 3 + p;
                bool ok = (p < 21) && (gp >= 0) && (gp < L);
                #pragma unroll
                for (int reg = 0; reg < 4; ++reg) {
                    int oc = wave*16 + quad*4 + reg;
                    float v = (1.f + cd[oc]) * (acc[j][reg] + kb1[oc]) + cd[64+oc];
                    h1[p][oc] = ok ? f2b(gelu(v)) : (u16)0;
                }
            }
        }
    }
    __syncthreads();

    {
        f4 acc[2];
        acc[0] = f4{0.f,0.f,0.f,0.f}; acc[1] = acc[0];
        const sh8* w2 = (const sh8*)wp2;
        #pragma unroll
        for (int c = 0; c < 6; ++c) {
            int kk = c >> 1, ic0 = (c & 1) << 5;
            sh8 A = w2[(c*4 + wave)*64 + lane];
            #pragma unroll
            for (int j = 0; j < 2; ++j) {
                int row = 1 + 16*j + nlo + kk;
                row = row > 21 ? 21 : row;
                sh8 Bv = *(const sh8*)&h1[row][ic0 + quad*8];
                acc[j] = __builtin_amdgcn_mfma_f32_16x16x32_bf16(A, Bv, acc[j], 0, 0, 0);
            }
        }
        #pragma unroll
        for (int j = 0; j < 2; ++j) {
            int q = 2 + 16*j + nlo;
            if (q < 20) {
                int gq = l0 - 3 + q;
                bool ok = (gq >= 0) && (gq < L);
                #pragma unroll
                for (int reg = 0; reg < 4; ++reg) {
                    int oc = wave*16 + quad*4 + reg;
                    h2[q][oc] = ok ? f2b(gelu(acc[j][reg] + kb2[oc])) : (u16)0;
                }
            }
        }
    }
    __syncthreads();

    f4 acc[4];
    #pragma unroll
    for (int mf = 0; mf < 4; ++mf) acc[mf] = f4{0.f,0.f,0.f,0.f};
    {
        const sh8* w3 = (const sh8*)wp3;
        #pragma unroll
        for (int c = 0; c < 6; ++c) {
            int kk = c >> 1, ic0 = (c & 1) << 5;
            int row = 2 + nlo + kk;
            sh8 Bv = *(const sh8*)&h2[row][ic0 + quad*8];
            #pragma unroll
            for (int mf = 0; mf < 4; ++mf) {
                sh8 A = w3[(c*16 + wave*4 + mf)*64 + lane];
                acc[mf] = __builtin_amdgcn_mfma_f32_16x16x32_bf16(A, Bv, acc[mf], 0, 0, 0);
            }
        }
    }
    {
        int gp = l0 + nlo;
        double s = 0.0;
        #pragma unroll
        for (int mf = 0; mf < 4; ++mf)
            #pragma unroll
            for (int reg = 0; reg < 4; ++reg) {
                int oc = (wave*4 + mf)*16 + quad*4 + reg;
                float dx = acc[mf][reg] + kb3[oc];
                s += (double)stacked[((size_t)b*CS + oc)*L + gp] * (double)dx;
            }
        #pragma unroll
        for (int off = 32; off > 0; off >>= 1) s += __shfl_down(s, off, 64);
        if (lane == 0) sred[wave] = s;
        __syncthreads();
        if (tid == 0) atomicAdd(&inner[b], sred[0] + sred[1] + sred[2] + sred[3]);
    }
}

// ---------- wavelet part ----------
__global__ __launch_bounds__(256) void rowmax_k(const float* __restrict__ a, float* __restrict__ bm) {
    __shared__ float red[256];
    int row = blockIdx.x;
    const float* p = a + (size_t)row * L;
    float m = -1e30f;
    for (int t = threadIdx.x; t < L; t += 256) m = fmaxf(m, p[t]);
    red[threadIdx.x] = m;
    __syncthreads();
    for (int s = 128; s > 0; s >>= 1) {
        if (threadIdx.x < s) red[threadIdx.x] = fmaxf(red[threadIdx.x], red[threadIdx.x + s]);
        __syncthreads();
    }
    if (threadIdx.x == 0) bm[row] = red[0];
}

__global__ __launch_bounds__(256) void mlp_k(const float* __restrict__ bm,
    const float* __restrict__ sw1, const float* __restrict__ sb1,
    const float* __restrict__ sw2, const float* __restrict__ sb2,
    const float* __restrict__ sw3, const float* __restrict__ sb3,
    float* __restrict__ filt) {
    __shared__ float m[8][64], f1[8][32], f2[8][32], raw[8][16], nrm[8][2];
    int tid = threadIdx.x;
    for (int i = tid; i < 512; i += 256) m[i >> 6][i & 63] = bm[i];
    __syncthreads();
    {
        int b = tid >> 5, h = tid & 31;
        float s = sb1[h];
        for (int c = 0; c < 64; ++c) s += m[b][c] * sw1[h*64+c];
        f1[b][h] = gelu(s);
    }
    __syncthreads();
    {
        int b = tid >> 5, h = tid & 31;
        float s = sb2[h];
        for (int k = 0; k < 32; ++k) s += f1[b][k] * sw2[h*32+k];
        f2[b][h] = gelu(s);
    }
    __syncthreads();
    if (tid < 128) {
        int b = tid >> 4, j = tid & 15;
        float s = sb3[j];
        for (int k = 0; k < 32; ++k) s += f2[b][k] * sw3[j*32+k];
        raw[b][j] = s;
    }
    __syncthreads();
    if (tid < 16) {
        int b = tid >> 1, half = tid & 1;
        float s = 0.f;
        for (int j = 0; j < 8; ++j) { float v = raw[b][half*8+j]; s += v*v; }
        nrm[b][half] = sqrtf(s);
    }
    __syncthreads();
    if (tid < 16) {
        int half = tid >> 3;
        float s = 0.f;
        for (int b = 0; b < 8; ++b) s += raw[b][tid] / nrm[b][half];
        filt[tid] = s * 0.125f;
    }
}

__global__ __launch_bounds__(256) void wconv_k(const float* __restrict__ ap,
    const float* __restrict__ filt, float* __restrict__ apOut,
    float* __restrict__ stacked, int lev) {
    __shared__ float f[16];
    if (threadIdx.x < 16) f[threadIdx.x] = filt[threadIdx.x];
    __syncthreads();
    size_t idx = (size_t)blockIdx.x * 256 + threadIdx.x;
    int l = (int)(idx & 2047);
    size_t bc = idx >> 11;
    int c = (int)(bc & 63), b = (int)(bc >> 6);
    const float* row = ap + (bc << 11);
    float lo = 0.f, hi = 0.f;
    #pragma unroll
    for (int k = 0; k < 8; ++k) {
        int mI = l + k - 3;
        mI = mI < 0 ? -mI : (mI >= L ? 2*L - 2 - mI : mI);
        float v = row[mI];
        lo += v * f[k];
        hi += v * f[8+k];
    }
    apOut[idx] = lo;
    stacked[((size_t)b * CS + (size_t)(lev+1) * 64 + c) * L + l] = hi;
}

__global__ __launch_bounds__(256) void copyx_k(const float* __restrict__ x, float* __restrict__ st) {
    size_t i = (size_t)blockIdx.x * 256 + threadIdx.x;
    size_t b = i >> 17, rem = i & 131071;
    st[b * ((size_t)CS*L) + rem] = x[i];
}

// stacked fp32 [b][c][l] -> ytr fp32 [b][l][c] + yb bf16 [b][l][c]
__global__ __launch_bounds__(256) void tinit_k(const float* __restrict__ st,
        float* __restrict__ ytr, u16* __restrict__ yb) {
    __shared__ float t[64][65];
    const int tid = threadIdx.x;
    const int l0 = blockIdx.x * 64, c0 = blockIdx.y * 64, b = blockIdx.z;
    #pragma unroll
    for (int k = 0; k < 16; ++k) {
        int c = k * 4 + (tid >> 6), l = tid & 63;
        t[c][l] = st[((size_t)b*CS + c0 + c) * L + l0 + l];
    }
    __syncthreads();
    #pragma unroll
    for (int k = 0; k < 16; ++k) {
        int p = k * 4 + (tid >> 6), ch = tid & 63;
        float v = t[ch][p];
        size_t ta = ((size_t)b * L + l0 + p) * 256 + c0 + ch;
        ytr[ta] = v;
        yb[ta] = f2b(v);
    }
}

__global__ void ecfin_k(const double* __restrict__ inner, float* __restrict__ out) {
    double s = 0.0;
    for (int b = 0; b < 8; ++b) s += inner[b] * inner[b];
    out[BCSL] = (float)(s / 8.0);
}

extern "C" void kernel_launch(void* const* d_in, const int* in_sizes, int n_in,
                              void* d_out, int out_size, void* d_ws, size_t ws_size,
                              hipStream_t stream) {
    const float* x   = (const float*)d_in[0];
    const float* sw1 = (const float*)d_in[1];
    const float* sb1 = (const float*)d_in[2];
    const float* sw2 = (const float*)d_in[3];
    const float* sb2 = (const float*)d_in[4];
    const float* sw3 = (const float*)d_in[5];
    const float* sb3 = (const float*)d_in[6];
    const float* tw1 = (const float*)d_in[7];
    const float* tb1 = (const float*)d_in[8];
    const float* tw2 = (const float*)d_in[9];
    const float* tb2 = (const float*)d_in[10];
    const float* cw  = (const float*)d_in[11];
    const float* cb  = (const float*)d_in[12];
    const float* k1  = (const float*)d_in[13];
    const float* kb1 = (const float*)d_in[14];
    const float* k2  = (const float*)d_in[15];
    const float* kb2 = (const float*)d_in[16];
    const float* k3  = (const float*)d_in[17];
    const float* kb3 = (const float*)d_in[18];
    float* out = (float*)d_out;

    char* cur = (char*)d_ws;
    auto alloc = [&](size_t bytes) { void* p = cur; cur += (bytes + 255) & ~(size_t)255; return p; };
    float* stacked = (float*)alloc(BCSL * 4);
    float* ytr     = (float*)alloc(BCSL * 4);
    u16*   yb0     = (u16*)  alloc(BCSL * 2);
    u16*   yb1     = (u16*)  alloc(BCSL * 2);
    u16*   sbuf[4];
    for (int i = 0; i < 4; ++i) sbuf[i] = (u16*)alloc(BCSL * 2);
    float* cond  = (float*)alloc(3200 * 4);
    float* bmax  = (float*)alloc(512 * 4);
    float* filt  = (float*)alloc(16 * 4);
    double* inner = (double*)alloc(8 * 8);
    u16* wp1 = (u16*)alloc(49152 * 2);
    u16* wp2 = (u16*)alloc(12288 * 2);
    u16* wp3 = (u16*)alloc(49152 * 2);

    u16 *s1b = sbuf[0], *s2b = sbuf[1], *s3b = sbuf[2], *s4b = sbuf[3];

    hipMemsetAsync(inner, 0, 8 * sizeof(double), stream);

    prep_k<<<192, 256, 0, stream>>>(k1, wp1, CS, C);
    prep_k<<<48,  256, 0, stream>>>(k2, wp2, C,  C);
    prep_k<<<192, 256, 0, stream>>>(k3, wp3, C,  CS);
    cond25_k<<<25, 128, 0, stream>>>(tw1, tb1, tw2, tb2, cw, cb, cond);

    // wavelet decomposition (s1b/s2b regions as fp32 scratch)
    copyx_k<<<4096, 256, 0, stream>>>(x, stacked);
    const float* apIn = x;
    float* apBuf[2] = {(float*)s1b, (float*)s2b};
    for (int lev = 0; lev < 3; ++lev) {
        rowmax_k<<<512, 256, 0, stream>>>(apIn, bmax);
        mlp_k<<<1, 256, 0, stream>>>(bmax, sw1, sb1, sw2, sb2, sw3, sb3, filt);
        float* apOut = apBuf[lev & 1];
        wconv_k<<<4096, 256, 0, stream>>>(apIn, filt, apOut, stacked, lev);
        apIn = apOut;
    }
    tinit_k<<<dim3(32, 4, 8), 256, 0, stream>>>(stacked, ytr, yb0);

    dim3 cg(128, 8);
    u16* ybI = yb0;
    u16* ybO = yb1;
    for (int i = 0; i < 4; ++i) {
        pair_k<0,0><<<cg, 256, 0, stream>>>(ybI, s1b, s2b, s3b, s4b, s1b, s2b,
            wp1, kb1, wp2, kb2, wp3, kb3, cond, i, nullptr, nullptr, nullptr);
        pair_k<1,0><<<cg, 256, 0, stream>>>(ybI, s1b, s2b, s3b, s4b, s3b, s4b,
            wp1, kb1, wp2, kb2, wp3, kb3, cond, i, nullptr, nullptr, nullptr);
        if (i < 3) {
            pair_k<2,0><<<cg, 256, 0, stream>>>(ybI, s1b, s2b, s3b, s4b, nullptr, nullptr,
                wp1, kb1, wp2, kb2, wp3, kb3, cond, i, ytr, ybO, nullptr);
        } else {
            pair_k<2,1><<<cg, 256, 0, stream>>>(ybI, s1b, s2b, s3b, s4b, nullptr, nullptr,
                wp1, kb1, wp2, kb2, wp3, kb3, cond, i, ytr, ybO, out);
        }
        u16* tmp = ybI; ybI = ybO; ybO = tmp;
    }

    // dx = ode_f(1.0, y) + ecloss
    dxec_k<<<cg, 256, 0, stream>>>(ybI, wp1, kb1, wp2, kb2, wp3, kb3, cond,
                                   stacked, inner);
    ecfin_k<<<1, 1, 0, stream>>>(inner, out);
}